// Round 9
// baseline (251.395 us; speedup 1.0000x reference)
//
#include <hip/hip_runtime.h>
#include <hip/hip_fp16.h>
#include <math.h>

#define C     128
#define C2U   64          // uints (2x bf16) per row
#define CHUNK 1024        // scan chunk per block (256 threads * 4)

typedef __attribute__((ext_vector_type(8))) short bf16x8;   // 8 bf16 = 4 VGPR
typedef __attribute__((ext_vector_type(4))) float f32x4;

union UV { uint4 u; bf16x8 h; };

// ---- bf16 helpers (manual RNE) ----
__device__ __forceinline__ unsigned int f2bf(float f) {
    unsigned int u = __float_as_uint(f);
    return (u + 0x7fffu + ((u >> 16) & 1u)) >> 16;
}
__device__ __forceinline__ float bflo(unsigned int v) { return __uint_as_float(v << 16); }
__device__ __forceinline__ float bfhi(unsigned int v) { return __uint_as_float(v & 0xffff0000u); }

// ---- packed edge: bits [16:0] = src (N < 2^17), bits [31:17] = fp16 w sans sign ----
__device__ __forceinline__ unsigned int pack_edge(int s, float w) {
    unsigned short hb = __half_as_ushort(__float2half(w));   // w > 0 -> sign bit 0
    return ((unsigned int)(hb & 0x7FFFu) << 17) | (unsigned int)s;
}
__device__ __forceinline__ int pk_src(unsigned int v) { return (int)(v & 0x1FFFFu); }
__device__ __forceinline__ float pk_w(unsigned int v) {
    return __half2float(__ushort_as_half((unsigned short)(v >> 17)));
}

// ---------------- x fp32 -> packed bf16 ----------------
__global__ __launch_bounds__(256) void ngl_cvt_kernel(const float4* __restrict__ x4,
                                                      uint4* __restrict__ xh4, int n8) {
    int t = blockIdx.x * blockDim.x + threadIdx.x;
    if (t >= n8) return;
    float4 a = x4[2 * t], b = x4[2 * t + 1];
    uint4 o;
    o.x = f2bf(a.x) | (f2bf(a.y) << 16);
    o.y = f2bf(a.z) | (f2bf(a.w) << 16);
    o.z = f2bf(b.x) | (f2bf(b.y) << 16);
    o.w = f2bf(b.z) | (f2bf(b.w) << 16);
    xh4[t] = o;
}

// ---------------- W fp32 -> W^T packed bf16 ----------------
__global__ __launch_bounds__(256) void ngl_wt_kernel(const float* __restrict__ W,
                                                     unsigned int* __restrict__ Wt) {
    int t = blockIdx.x * blockDim.x + threadIdx.x;   // 128*64
    if (t >= C * C2U) return;
    int col = t >> 6, k2 = t & 63;
    float w0 = W[(2 * k2) * C + col];
    float w1 = W[(2 * k2 + 1) * C + col];
    Wt[col * C2U + k2] = f2bf(w0) | (f2bf(w1) << 16);
}

// ---------------- degree + slot (fused counting-sort rank) ----------------
__global__ void ngl_deg_kernel(const int* __restrict__ dst, int E,
                               int* __restrict__ deg, unsigned short* __restrict__ slot) {
    int e = blockIdx.x * blockDim.x + threadIdx.x;
    if (e < E) slot[e] = (unsigned short)atomicAdd(&deg[dst[e]], 1);
}

// scan pass A: per-block sum of deg chunk; fused dis[i] = rsqrt(deg[i]+1)
__global__ __launch_bounds__(256) void ngl_bsum_dis_kernel(
        const int* __restrict__ deg, float* __restrict__ dis,
        int* __restrict__ bsum, int N) {
    __shared__ int red[256];
    int t = threadIdx.x;
    int base = blockIdx.x * CHUNK + t * 4;
    int s = 0;
    #pragma unroll
    for (int j = 0; j < 4; ++j) {
        int i = base + j;
        if (i < N) {
            int dv = deg[i];
            s += dv;
            dis[i] = rsqrtf((float)(dv + 1));
        }
    }
    red[t] = s;
    __syncthreads();
    for (int o = 128; o > 0; o >>= 1) {
        if (t < o) red[t] += red[t + o];
        __syncthreads();
    }
    if (t == 0) bsum[blockIdx.x] = red[0];
}

// scan pass B: exclusive scan of block sums (NB <= 256)
__global__ __launch_bounds__(256) void ngl_bscan_kernel(int* __restrict__ bsum, int NB) {
    __shared__ int s[256];
    int t = threadIdx.x;
    s[t] = (t < NB) ? bsum[t] : 0;
    __syncthreads();
    for (int o = 1; o < 256; o <<= 1) {
        int v = 0;
        if (t >= o) v = s[t - o];
        __syncthreads();
        if (t >= o) s[t] += v;
        __syncthreads();
    }
    if (t < NB) bsum[t] = (t == 0) ? 0 : s[t - 1];
}

// scan pass C: per-block scan + block offset -> exclusive offset[]
__global__ __launch_bounds__(256) void ngl_offset_kernel(
        const int* __restrict__ deg, const int* __restrict__ boff,
        int* __restrict__ offset, int N) {
    __shared__ int red[256];
    int t = threadIdx.x;
    int base = blockIdx.x * CHUNK + t * 4;
    int v[4];
    int s = 0;
    #pragma unroll
    for (int j = 0; j < 4; ++j) {
        int i = base + j;
        v[j] = (i < N) ? deg[i] : 0;
        s += v[j];
    }
    red[t] = s;
    __syncthreads();
    for (int o = 1; o < 256; o <<= 1) {
        int u = 0;
        if (t >= o) u = red[t - o];
        __syncthreads();
        if (t >= o) red[t] += u;
        __syncthreads();
    }
    int run = boff[blockIdx.x] + ((t == 0) ? 0 : red[t - 1]);
    #pragma unroll
    for (int j = 0; j < 4; ++j) {
        int i = base + j;
        if (i < N) {
            offset[i] = run;
            run += v[j];
        }
    }
}

// counting-sort scatter (atomic-free): payload[offset[d]+slot[e]] = pack{w,src}
__global__ void ngl_sort_kernel(const int* __restrict__ src, const int* __restrict__ dst, int E,
                                const float* __restrict__ dis, const int* __restrict__ offset,
                                const unsigned short* __restrict__ slot,
                                unsigned int* __restrict__ payload) {
    int e = blockIdx.x * blockDim.x + threadIdx.x;
    if (e >= E) return;
    int s = src[e], d = dst[e];
    int pos = offset[d] + (int)slot[e];
    float w = dis[s] * dis[d];
    __builtin_nontemporal_store(pack_edge(s, w), &payload[pos]);
}

// one wave per node; 8-deep software pipeline: 8 payload entries + 8 random
// 256B x-row loads in flight per wave (MLP against L2/L3 latency).
__global__ __launch_bounds__(256) void ngl_gather_kernel(
        const unsigned int* __restrict__ xh, const float* __restrict__ dis,
        const int* __restrict__ offset, const int* __restrict__ deg,
        const unsigned int* __restrict__ payload, unsigned int* __restrict__ agg, int N) {
    int node = blockIdx.x * 4 + (threadIdx.x >> 6);
    int lane = threadIdx.x & 63;
    if (node >= N) return;

    float dn = dis[node];
    float w0 = dn * dn;                       // self-loop norm
    unsigned int sv = xh[(long long)node * C2U + lane];
    float accx = w0 * bflo(sv);
    float accy = w0 * bfhi(sv);

    int beg = offset[node];
    int cnt = deg[node];

    unsigned int e[8];
    int i = 0;
    if (cnt >= 8) {
        #pragma unroll
        for (int j = 0; j < 8; ++j) e[j] = __builtin_nontemporal_load(&payload[beg + j]);
        while (i + 8 <= cnt) {
            unsigned int c[8];
            #pragma unroll
            for (int j = 0; j < 8; ++j) c[j] = e[j];
            if (i + 16 <= cnt) {
                #pragma unroll
                for (int j = 0; j < 8; ++j)
                    e[j] = __builtin_nontemporal_load(&payload[beg + i + 8 + j]);
            }
            unsigned int v[8];
            #pragma unroll
            for (int j = 0; j < 8; ++j)
                v[j] = xh[(long long)pk_src(c[j]) * C2U + lane];
            #pragma unroll
            for (int j = 0; j < 8; ++j) {
                float f = pk_w(c[j]);
                accx += f * bflo(v[j]);
                accy += f * bfhi(v[j]);
            }
            i += 8;
        }
    }
    for (; i < cnt; ++i) {
        unsigned int cur = __builtin_nontemporal_load(&payload[beg + i]);
        float w = pk_w(cur);
        unsigned int v = xh[(long long)pk_src(cur) * C2U + lane];
        accx += w * bflo(v);
        accy += w * bfhi(v);
    }
    agg[(long long)node * C2U + lane] = f2bf(accx) | (f2bf(accy) << 16);
}

__device__ __forceinline__ float silu1(float v) {
    return v / (1.0f + __expf(-v));
}

// ---------------- MFMA GEMM: out = silu(agg @ W + b) ----------------
__global__ __launch_bounds__(256, 2) void ngl_mfma_gemm_kernel(
        const uint4* __restrict__ agg4, const uint4* __restrict__ wt4,
        const float* __restrict__ bias, float* __restrict__ out,
        int N, int tiles_total) {
    int wid  = threadIdx.x >> 6;
    int lane = threadIdx.x & 63;
    int r  = lane & 15;       // row-in-tile (A) / col-in-tile (B,D)
    int kg = lane >> 4;       // k-group 0..3

    bf16x8 bfr[8][4];
    #pragma unroll
    for (int nt = 0; nt < 8; ++nt) {
        #pragma unroll
        for (int kk = 0; kk < 4; ++kk) {
            UV u; u.u = wt4[(nt * 16 + r) * 16 + kk * 4 + kg];
            bfr[nt][kk] = u.h;
        }
    }
    float bv[8];
    #pragma unroll
    for (int nt = 0; nt < 8; ++nt) bv[nt] = bias[nt * 16 + r];

    for (int tile = blockIdx.x * 4 + wid; tile < tiles_total; tile += gridDim.x * 4) {
        int row0 = tile * 16;
        int arow = row0 + r;

        bf16x8 afr[4];
        #pragma unroll
        for (int kk = 0; kk < 4; ++kk) {
            UV u;
            u.u = (arow < N) ? agg4[(long long)arow * 16 + kk * 4 + kg]
                             : make_uint4(0, 0, 0, 0);
            afr[kk] = u.h;
        }

        f32x4 acc[8];
        #pragma unroll
        for (int nt = 0; nt < 8; ++nt) acc[nt] = (f32x4){0.f, 0.f, 0.f, 0.f};

        #pragma unroll
        for (int kk = 0; kk < 4; ++kk) {
            #pragma unroll
            for (int nt = 0; nt < 8; ++nt) {
                acc[nt] = __builtin_amdgcn_mfma_f32_16x16x32_bf16(
                    afr[kk], bfr[nt][kk], acc[nt], 0, 0, 0);
            }
        }

        #pragma unroll
        for (int nt = 0; nt < 8; ++nt) {
            #pragma unroll
            for (int j = 0; j < 4; ++j) {
                int rr = row0 + kg * 4 + j;
                if (rr < N)
                    __builtin_nontemporal_store(
                        silu1(acc[nt][j] + bv[nt]),
                        &out[(long long)rr * C + nt * 16 + r]);
            }
        }
    }
}

extern "C" void kernel_launch(void* const* d_in, const int* in_sizes, int n_in,
                              void* d_out, int out_size, void* d_ws, size_t ws_size,
                              hipStream_t stream) {
    const float* x = (const float*)d_in[0];
    const int*   ei = (const int*)d_in[1];
    const float* W = (const float*)d_in[2];
    const float* b = (const float*)d_in[3];

    int N = in_sizes[0] / C;
    int E = in_sizes[1] / 2;
    const int* src = ei;
    const int* dst = ei + E;

    char* ws = (char*)d_ws;
    size_t off = 0;
    unsigned int* xh = (unsigned int*)(ws + off);  off += (size_t)N * C * 2;  // 25.6 MB
    unsigned int* agg = (unsigned int*)(ws + off); off += (size_t)N * C * 2;  // 25.6 MB
    unsigned int* payload = (unsigned int*)(ws + off); off += (size_t)E * 4;  // 6.4 MB
    unsigned short* slot = (unsigned short*)(ws + off); off += (size_t)E * 2; // 3.2 MB
    int* deg = (int*)(ws + off);                   off += (size_t)N * 4;
    int* offset = (int*)(ws + off);                off += (size_t)N * 4;
    float* dis = (float*)(ws + off);               off += (size_t)N * 4;
    int* bsum = (int*)(ws + off);                  off += 1024 * 4;
    unsigned int* Wt = (unsigned int*)(ws + off);  off += (size_t)C * C2U * 4;

    int NB = (N + CHUNK - 1) / CHUNK;     // 98 blocks for N=100k (<=256 required)

    (void)hipMemsetAsync(deg, 0, (size_t)N * 4, stream);

    int n8 = N * C / 8;
    ngl_cvt_kernel<<<(n8 + 255) / 256, 256, 0, stream>>>(
        (const float4*)x, (uint4*)xh, n8);
    ngl_wt_kernel<<<(C * C2U + 255) / 256, 256, 0, stream>>>(W, Wt);
    ngl_deg_kernel<<<(E + 255) / 256, 256, 0, stream>>>(dst, E, deg, slot);
    ngl_bsum_dis_kernel<<<NB, 256, 0, stream>>>(deg, dis, bsum, N);
    ngl_bscan_kernel<<<1, 256, 0, stream>>>(bsum, NB);
    ngl_offset_kernel<<<NB, 256, 0, stream>>>(deg, bsum, offset, N);
    ngl_sort_kernel<<<(E + 255) / 256, 256, 0, stream>>>(src, dst, E, dis, offset, slot, payload);
    ngl_gather_kernel<<<(N + 3) / 4, 256, 0, stream>>>(
        xh, dis, offset, deg, payload, agg, N);

    int tiles = (N + 15) / 16;            // 6250
    ngl_mfma_gemm_kernel<<<512, 256, 0, stream>>>(
        (const uint4*)agg, (const uint4*)Wt, b, (float*)d_out, N, tiles);
}

// Round 10
// 227.865 us; speedup vs baseline: 1.1033x; 1.1033x over previous
//
#include <hip/hip_runtime.h>
#include <hip/hip_fp16.h>
#include <math.h>

#define C     128
#define C2U   64          // uints (2x bf16) per row
#define CHUNK 1024        // scan chunk per block (256 threads * 4)

typedef __attribute__((ext_vector_type(8))) short bf16x8;   // 8 bf16 = 4 VGPR
typedef __attribute__((ext_vector_type(4))) float f32x4;

union UV { uint4 u; bf16x8 h; };

// ---- bf16 helpers (manual RNE) ----
__device__ __forceinline__ unsigned int f2bf(float f) {
    unsigned int u = __float_as_uint(f);
    return (u + 0x7fffu + ((u >> 16) & 1u)) >> 16;
}
__device__ __forceinline__ float bflo(unsigned int v) { return __uint_as_float(v << 16); }
__device__ __forceinline__ float bfhi(unsigned int v) { return __uint_as_float(v & 0xffff0000u); }

// ---- packed edge: bits [16:0] = src (N < 2^17), bits [31:17] = fp16 w sans sign ----
__device__ __forceinline__ unsigned int pack_edge(int s, float w) {
    unsigned short hb = __half_as_ushort(__float2half(w));   // w > 0 -> sign bit 0
    return ((unsigned int)(hb & 0x7FFFu) << 17) | (unsigned int)s;
}
__device__ __forceinline__ int pk_src(unsigned int v) { return (int)(v & 0x1FFFFu); }
__device__ __forceinline__ float pk_w(unsigned int v) {
    return __half2float(__ushort_as_half((unsigned short)(v >> 17)));
}

// ---------------- fused: x fp32 -> packed bf16 ; W -> W^T packed bf16 ----------------
__global__ __launch_bounds__(256) void ngl_cvtwt_kernel(
        const float4* __restrict__ x4, uint4* __restrict__ xh4, int n8,
        const float* __restrict__ W, unsigned int* __restrict__ Wt) {
    int t = blockIdx.x * blockDim.x + threadIdx.x;
    if (t < n8) {
        float4 a = x4[2 * t], b = x4[2 * t + 1];
        uint4 o;
        o.x = f2bf(a.x) | (f2bf(a.y) << 16);
        o.y = f2bf(a.z) | (f2bf(a.w) << 16);
        o.z = f2bf(b.x) | (f2bf(b.y) << 16);
        o.w = f2bf(b.z) | (f2bf(b.w) << 16);
        xh4[t] = o;
    } else {
        int u = t - n8;                        // 0 .. C*C2U-1
        if (u < C * C2U) {
            int col = u >> 6, k2 = u & 63;
            float w0 = W[(2 * k2) * C + col];
            float w1 = W[(2 * k2 + 1) * C + col];
            Wt[col * C2U + k2] = f2bf(w0) | (f2bf(w1) << 16);
        }
    }
}

// ---------------- degree + slot (fused counting-sort rank) ----------------
__global__ void ngl_deg_kernel(const int* __restrict__ dst, int E,
                               int* __restrict__ deg, unsigned short* __restrict__ slot) {
    int e = blockIdx.x * blockDim.x + threadIdx.x;
    if (e < E) slot[e] = (unsigned short)atomicAdd(&deg[dst[e]], 1);
}

// scan pass A: per-block sum of deg chunk; fused dis[i] = rsqrt(deg[i]+1)
__global__ __launch_bounds__(256) void ngl_bsum_dis_kernel(
        const int* __restrict__ deg, float* __restrict__ dis,
        int* __restrict__ bsum, int N) {
    __shared__ int red[256];
    int t = threadIdx.x;
    int base = blockIdx.x * CHUNK + t * 4;
    int s = 0;
    #pragma unroll
    for (int j = 0; j < 4; ++j) {
        int i = base + j;
        if (i < N) {
            int dv = deg[i];
            s += dv;
            dis[i] = rsqrtf((float)(dv + 1));
        }
    }
    red[t] = s;
    __syncthreads();
    for (int o = 128; o > 0; o >>= 1) {
        if (t < o) red[t] += red[t + o];
        __syncthreads();
    }
    if (t == 0) bsum[blockIdx.x] = red[0];
}

// scan pass C (with inline scan of the <=256 block sums, replaces pass B):
__global__ __launch_bounds__(256) void ngl_offset_kernel(
        const int* __restrict__ deg, const int* __restrict__ bsum,
        int* __restrict__ offset, int N, int NB) {
    __shared__ int pre[256];
    __shared__ int red[256];
    int t = threadIdx.x;
    pre[t] = (t < NB) ? bsum[t] : 0;
    __syncthreads();
    for (int o = 1; o < 256; o <<= 1) {
        int v = 0;
        if (t >= o) v = pre[t - o];
        __syncthreads();
        if (t >= o) pre[t] += v;
        __syncthreads();
    }
    int boff = (blockIdx.x == 0) ? 0 : pre[blockIdx.x - 1];

    int base = blockIdx.x * CHUNK + t * 4;
    int v[4];
    int s = 0;
    #pragma unroll
    for (int j = 0; j < 4; ++j) {
        int i = base + j;
        v[j] = (i < N) ? deg[i] : 0;
        s += v[j];
    }
    red[t] = s;
    __syncthreads();
    for (int o = 1; o < 256; o <<= 1) {
        int u = 0;
        if (t >= o) u = red[t - o];
        __syncthreads();
        if (t >= o) red[t] += u;
        __syncthreads();
    }
    int run = boff + ((t == 0) ? 0 : red[t - 1]);
    #pragma unroll
    for (int j = 0; j < 4; ++j) {
        int i = base + j;
        if (i < N) {
            offset[i] = run;
            run += v[j];
        }
    }
}

// counting-sort scatter (atomic-free): payload[offset[d]+slot[e]] = pack{w,src}
__global__ void ngl_sort_kernel(const int* __restrict__ src, const int* __restrict__ dst, int E,
                                const float* __restrict__ dis, const int* __restrict__ offset,
                                const unsigned short* __restrict__ slot,
                                unsigned int* __restrict__ payload) {
    int e = blockIdx.x * blockDim.x + threadIdx.x;
    if (e >= E) return;
    int s = src[e], d = dst[e];
    int pos = offset[d] + (int)slot[e];
    float w = dis[s] * dis[d];
    __builtin_nontemporal_store(pack_edge(s, w), &payload[pos]);
}

// one wave per node; 4-deep software pipeline (measured best): 4 payload
// entries + 4 random 256B x-row loads in flight per wave.
__global__ __launch_bounds__(256) void ngl_gather_kernel(
        const unsigned int* __restrict__ xh, const float* __restrict__ dis,
        const int* __restrict__ offset, const int* __restrict__ deg,
        const unsigned int* __restrict__ payload, unsigned int* __restrict__ agg, int N) {
    int node = blockIdx.x * 4 + (threadIdx.x >> 6);
    int lane = threadIdx.x & 63;
    if (node >= N) return;

    float dn = dis[node];
    float w0 = dn * dn;                       // self-loop norm
    unsigned int sv = xh[(long long)node * C2U + lane];
    float accx = w0 * bflo(sv);
    float accy = w0 * bfhi(sv);

    int beg = offset[node];
    int cnt = deg[node];

    unsigned int e0, e1, e2, e3;
    int i = 0;
    if (cnt >= 4) {
        e0 = payload[beg + 0]; e1 = payload[beg + 1];
        e2 = payload[beg + 2]; e3 = payload[beg + 3];
        while (i + 4 <= cnt) {
            unsigned int c0 = e0, c1 = e1, c2 = e2, c3 = e3;
            int nb = beg + i + 4;
            if (i + 8 <= cnt) {                 // prefetch next payload group
                e0 = payload[nb + 0]; e1 = payload[nb + 1];
                e2 = payload[nb + 2]; e3 = payload[nb + 3];
            }
            unsigned int v0 = xh[(long long)pk_src(c0) * C2U + lane];
            unsigned int v1 = xh[(long long)pk_src(c1) * C2U + lane];
            unsigned int v2 = xh[(long long)pk_src(c2) * C2U + lane];
            unsigned int v3 = xh[(long long)pk_src(c3) * C2U + lane];
            float f0 = pk_w(c0), f1 = pk_w(c1), f2 = pk_w(c2), f3 = pk_w(c3);
            accx += f0 * bflo(v0); accy += f0 * bfhi(v0);
            accx += f1 * bflo(v1); accy += f1 * bfhi(v1);
            accx += f2 * bflo(v2); accy += f2 * bfhi(v2);
            accx += f3 * bflo(v3); accy += f3 * bfhi(v3);
            i += 4;
        }
    }
    for (; i < cnt; ++i) {
        unsigned int cur = payload[beg + i];
        float w = pk_w(cur);
        unsigned int v = xh[(long long)pk_src(cur) * C2U + lane];
        accx += w * bflo(v);
        accy += w * bfhi(v);
    }
    agg[(long long)node * C2U + lane] = f2bf(accx) | (f2bf(accy) << 16);
}

__device__ __forceinline__ float silu1(float v) {
    return v / (1.0f + __expf(-v));
}

// ---------------- MFMA GEMM: out = silu(agg @ W + b) ----------------
__global__ __launch_bounds__(256, 2) void ngl_mfma_gemm_kernel(
        const uint4* __restrict__ agg4, const uint4* __restrict__ wt4,
        const float* __restrict__ bias, float* __restrict__ out,
        int N, int tiles_total) {
    int wid  = threadIdx.x >> 6;
    int lane = threadIdx.x & 63;
    int r  = lane & 15;       // row-in-tile (A) / col-in-tile (B,D)
    int kg = lane >> 4;       // k-group 0..3

    bf16x8 bfr[8][4];
    #pragma unroll
    for (int nt = 0; nt < 8; ++nt) {
        #pragma unroll
        for (int kk = 0; kk < 4; ++kk) {
            UV u; u.u = wt4[(nt * 16 + r) * 16 + kk * 4 + kg];
            bfr[nt][kk] = u.h;
        }
    }
    float bv[8];
    #pragma unroll
    for (int nt = 0; nt < 8; ++nt) bv[nt] = bias[nt * 16 + r];

    for (int tile = blockIdx.x * 4 + wid; tile < tiles_total; tile += gridDim.x * 4) {
        int row0 = tile * 16;
        int arow = row0 + r;

        bf16x8 afr[4];
        #pragma unroll
        for (int kk = 0; kk < 4; ++kk) {
            UV u;
            u.u = (arow < N) ? agg4[(long long)arow * 16 + kk * 4 + kg]
                             : make_uint4(0, 0, 0, 0);
            afr[kk] = u.h;
        }

        f32x4 acc[8];
        #pragma unroll
        for (int nt = 0; nt < 8; ++nt) acc[nt] = (f32x4){0.f, 0.f, 0.f, 0.f};

        #pragma unroll
        for (int kk = 0; kk < 4; ++kk) {
            #pragma unroll
            for (int nt = 0; nt < 8; ++nt) {
                acc[nt] = __builtin_amdgcn_mfma_f32_16x16x32_bf16(
                    afr[kk], bfr[nt][kk], acc[nt], 0, 0, 0);
            }
        }

        #pragma unroll
        for (int nt = 0; nt < 8; ++nt) {
            #pragma unroll
            for (int j = 0; j < 4; ++j) {
                int rr = row0 + kg * 4 + j;
                if (rr < N)
                    __builtin_nontemporal_store(
                        silu1(acc[nt][j] + bv[nt]),
                        &out[(long long)rr * C + nt * 16 + r]);
            }
        }
    }
}

extern "C" void kernel_launch(void* const* d_in, const int* in_sizes, int n_in,
                              void* d_out, int out_size, void* d_ws, size_t ws_size,
                              hipStream_t stream) {
    const float* x = (const float*)d_in[0];
    const int*   ei = (const int*)d_in[1];
    const float* W = (const float*)d_in[2];
    const float* b = (const float*)d_in[3];

    int N = in_sizes[0] / C;
    int E = in_sizes[1] / 2;
    const int* src = ei;
    const int* dst = ei + E;

    char* ws = (char*)d_ws;
    size_t off = 0;
    unsigned int* xh = (unsigned int*)(ws + off);  off += (size_t)N * C * 2;  // 25.6 MB
    unsigned int* agg = (unsigned int*)(ws + off); off += (size_t)N * C * 2;  // 25.6 MB
    unsigned int* payload = (unsigned int*)(ws + off); off += (size_t)E * 4;  // 6.4 MB
    unsigned short* slot = (unsigned short*)(ws + off); off += (size_t)E * 2; // 3.2 MB
    int* deg = (int*)(ws + off);                   off += (size_t)N * 4;
    int* offset = (int*)(ws + off);                off += (size_t)N * 4;
    float* dis = (float*)(ws + off);               off += (size_t)N * 4;
    int* bsum = (int*)(ws + off);                  off += 1024 * 4;
    unsigned int* Wt = (unsigned int*)(ws + off);  off += (size_t)C * C2U * 4;

    int NB = (N + CHUNK - 1) / CHUNK;     // 98 blocks for N=100k (<=256 required)

    (void)hipMemsetAsync(deg, 0, (size_t)N * 4, stream);

    int n8 = N * C / 8;
    int cw = n8 + C * C2U;
    ngl_cvtwt_kernel<<<(cw + 255) / 256, 256, 0, stream>>>(
        (const float4*)x, (uint4*)xh, n8, W, Wt);
    ngl_deg_kernel<<<(E + 255) / 256, 256, 0, stream>>>(dst, E, deg, slot);
    ngl_bsum_dis_kernel<<<NB, 256, 0, stream>>>(deg, dis, bsum, N);
    ngl_offset_kernel<<<NB, 256, 0, stream>>>(deg, bsum, offset, N, NB);
    ngl_sort_kernel<<<(E + 255) / 256, 256, 0, stream>>>(src, dst, E, dis, offset, slot, payload);
    ngl_gather_kernel<<<(N + 3) / 4, 256, 0, stream>>>(
        xh, dis, offset, deg, payload, agg, N);

    int tiles = (N + 15) / 16;            // 6250
    ngl_mfma_gemm_kernel<<<512, 256, 0, stream>>>(
        (const uint4*)agg, (const uint4*)Wt, b, (float*)d_out, N, tiles);
}

// Round 11
// 187.575 us; speedup vs baseline: 1.3402x; 1.2148x over previous
//
#include <hip/hip_runtime.h>
#include <hip/hip_fp16.h>
#include <math.h>

#define C      128
#define C2U    64         // uints (2x bf16) per row
#define BSH    7          // 128 nodes per coarse bucket
#define BNODES 128
#define CHUNKE 16384      // edges per coarse block

typedef __attribute__((ext_vector_type(8))) short bf16x8;   // 8 bf16 = 4 VGPR
typedef __attribute__((ext_vector_type(4))) float f32x4;

union UV { uint4 u; bf16x8 h; };

// ---- bf16 helpers (manual RNE) ----
__device__ __forceinline__ unsigned int f2bf(float f) {
    unsigned int u = __float_as_uint(f);
    return (u + 0x7fffu + ((u >> 16) & 1u)) >> 16;
}
__device__ __forceinline__ float bflo(unsigned int v) { return __uint_as_float(v << 16); }
__device__ __forceinline__ float bfhi(unsigned int v) { return __uint_as_float(v & 0xffff0000u); }

// ---- packed edge: bits [16:0] = src (N < 2^17), bits [31:17] = fp16 w sans sign ----
__device__ __forceinline__ unsigned int pack_edge(int s, float w) {
    unsigned short hb = __half_as_ushort(__float2half(w));   // w > 0 -> sign bit 0
    return ((unsigned int)(hb & 0x7FFFu) << 17) | (unsigned int)s;
}
__device__ __forceinline__ int pk_src(unsigned int v) { return (int)(v & 0x1FFFFu); }
__device__ __forceinline__ float pk_w(unsigned int v) {
    return __half2float(__ushort_as_half((unsigned short)(v >> 17)));
}

// ---------------- fused: x fp32 -> packed bf16 ; W -> W^T packed bf16 ----------------
__global__ __launch_bounds__(256) void ngl_cvtwt_kernel(
        const float4* __restrict__ x4, uint4* __restrict__ xh4, int n8,
        const float* __restrict__ W, unsigned int* __restrict__ Wt) {
    int t = blockIdx.x * blockDim.x + threadIdx.x;
    if (t < n8) {
        float4 a = x4[2 * t], b = x4[2 * t + 1];
        uint4 o;
        o.x = f2bf(a.x) | (f2bf(a.y) << 16);
        o.y = f2bf(a.z) | (f2bf(a.w) << 16);
        o.z = f2bf(b.x) | (f2bf(b.y) << 16);
        o.w = f2bf(b.z) | (f2bf(b.w) << 16);
        xh4[t] = o;
    } else {
        int u = t - n8;                        // 0 .. C*C2U-1
        if (u < C * C2U) {
            int col = u >> 6, k2 = u & 63;
            float w0 = W[(2 * k2) * C + col];
            float w1 = W[(2 * k2 + 1) * C + col];
            Wt[col * C2U + k2] = f2bf(w0) | (f2bf(w1) << 16);
        }
    }
}

// ---------------- a1: coarse histogram (LDS atomics only) ----------------
__global__ __launch_bounds__(256) void ngl_chist_kernel(
        const int* __restrict__ dst, int E, int NBUCK, int NBLK, int* __restrict__ cnt) {
    extern __shared__ int h[];
    for (int i = threadIdx.x; i < NBUCK; i += 256) h[i] = 0;
    __syncthreads();
    int base = blockIdx.x * CHUNKE;
    int end = base + CHUNKE; if (end > E) end = E;
    for (int i = base + threadIdx.x; i < end; i += 256)
        atomicAdd(&h[dst[i] >> BSH], 1);
    __syncthreads();
    for (int i = threadIdx.x; i < NBUCK; i += 256)
        cnt[i * NBLK + blockIdx.x] = h[i];
}

// ---------------- a2: hierarchical exclusive scan of cnt[M] ----------------
__global__ __launch_bounds__(256) void ngl_s1_kernel(const int* __restrict__ in,
                                                     int* __restrict__ bsum, int M) {
    __shared__ int red[256];
    int t = threadIdx.x;
    int base = blockIdx.x * 1024 + t * 4;
    int s = 0;
    #pragma unroll
    for (int j = 0; j < 4; ++j) {
        int i = base + j;
        if (i < M) s += in[i];
    }
    red[t] = s;
    __syncthreads();
    for (int o = 128; o > 0; o >>= 1) {
        if (t < o) red[t] += red[t + o];
        __syncthreads();
    }
    if (t == 0) bsum[blockIdx.x] = red[0];
}

__global__ __launch_bounds__(256) void ngl_s2_kernel(
        const int* __restrict__ in, const int* __restrict__ bsum,
        int* __restrict__ out, int M, int NB) {
    __shared__ int pre[256];
    __shared__ int red[256];
    int t = threadIdx.x;
    pre[t] = (t < NB) ? bsum[t] : 0;
    __syncthreads();
    for (int o = 1; o < 256; o <<= 1) {
        int v = 0;
        if (t >= o) v = pre[t - o];
        __syncthreads();
        if (t >= o) pre[t] += v;
        __syncthreads();
    }
    int boff = (blockIdx.x == 0) ? 0 : pre[blockIdx.x - 1];

    int base = blockIdx.x * 1024 + t * 4;
    int v[4];
    int s = 0;
    #pragma unroll
    for (int j = 0; j < 4; ++j) {
        int i = base + j;
        v[j] = (i < M) ? in[i] : 0;
        s += v[j];
    }
    red[t] = s;
    __syncthreads();
    for (int o = 1; o < 256; o <<= 1) {
        int u = 0;
        if (t >= o) u = red[t - o];
        __syncthreads();
        if (t >= o) red[t] += u;
        __syncthreads();
    }
    int run = boff + ((t == 0) ? 0 : red[t - 1]);
    #pragma unroll
    for (int j = 0; j < 4; ++j) {
        int i = base + j;
        if (i < M) {
            out[i] = run;
            run += v[j];
        }
    }
}

// ---------------- a3: coarse scatter to exact scanned positions ----------------
// pk24 = src (17 bits) | dstloc (7 bits) << 17
__global__ __launch_bounds__(256) void ngl_cscat_kernel(
        const int* __restrict__ src, const int* __restrict__ dst, int E,
        int NBUCK, int NBLK, const int* __restrict__ cntoff,
        unsigned int* __restrict__ pk) {
    extern __shared__ int cur[];
    int blk = blockIdx.x;
    for (int i = threadIdx.x; i < NBUCK; i += 256) cur[i] = cntoff[i * NBLK + blk];
    __syncthreads();
    int base = blk * CHUNKE;
    int end = base + CHUNKE; if (end > E) end = E;
    for (int i = base + threadIdx.x; i < end; i += 256) {
        int d = dst[i];
        int b = d >> BSH;
        int pos = atomicAdd(&cur[b], 1);
        pk[pos] = (unsigned int)src[i] | ((unsigned int)(d & (BNODES - 1)) << 17);
    }
}

// ---------------- f1: per-bucket fine histogram -> deg, dis ----------------
__global__ __launch_bounds__(256) void ngl_f1_kernel(
        const unsigned int* __restrict__ pk, const int* __restrict__ cntoff,
        int NBLK, int E, int N,
        int* __restrict__ deg, float* __restrict__ dis) {
    __shared__ int h[BNODES];
    int b = blockIdx.x, nb = gridDim.x;
    int s = cntoff[b * NBLK];
    int e = (b + 1 < nb) ? cntoff[(b + 1) * NBLK] : E;
    int t = threadIdx.x;
    if (t < BNODES) h[t] = 0;
    __syncthreads();
    for (int i = s + t; i < e; i += 256)
        atomicAdd(&h[pk[i] >> 17], 1);
    __syncthreads();
    if (t < BNODES) {
        int n = b * BNODES + t;
        if (n < N) {
            int dv = h[t];
            deg[n] = dv;
            dis[n] = rsqrtf((float)(dv + 1));
        }
    }
}

// ---------------- f2: per-bucket fine sort -> offset, payload{w,src} ----------------
__global__ __launch_bounds__(256) void ngl_f2_kernel(
        const unsigned int* __restrict__ pk, const int* __restrict__ cntoff,
        int NBLK, int E, int N, const float* __restrict__ dis,
        int* __restrict__ offset, unsigned int* __restrict__ payload) {
    __shared__ int h[BNODES];
    __shared__ int sc[BNODES];
    __shared__ int cur[BNODES];
    __shared__ float dl[BNODES];
    int b = blockIdx.x, nb = gridDim.x;
    int s = cntoff[b * NBLK];
    int e = (b + 1 < nb) ? cntoff[(b + 1) * NBLK] : E;
    int t = threadIdx.x;
    if (t < BNODES) {
        h[t] = 0;
        int n = b * BNODES + t;
        dl[t] = (n < N) ? dis[n] : 0.f;
    }
    __syncthreads();
    for (int i = s + t; i < e; i += 256)
        atomicAdd(&h[pk[i] >> 17], 1);
    __syncthreads();
    if (t < BNODES) sc[t] = h[t];
    __syncthreads();
    for (int o = 1; o < BNODES; o <<= 1) {
        int v = 0;
        if (t < BNODES && t >= o) v = sc[t - o];
        __syncthreads();
        if (t < BNODES && t >= o) sc[t] += v;
        __syncthreads();
    }
    if (t < BNODES) {
        int ex = (t == 0) ? 0 : sc[t - 1];
        cur[t] = ex;
        int n = b * BNODES + t;
        if (n < N) offset[n] = s + ex;
    }
    __syncthreads();
    for (int i = s + t; i < e; i += 256) {
        unsigned int p = pk[i];
        int loc = (int)(p >> 17);
        int sr = (int)(p & 0x1FFFFu);
        int pos = s + atomicAdd(&cur[loc], 1);
        float w = dis[sr] * dl[loc];
        payload[pos] = pack_edge(sr, w);
    }
}

// one wave per node; 4-deep software pipeline (measured best): 4 payload
// entries + 4 random 256B x-row loads in flight per wave.
__global__ __launch_bounds__(256) void ngl_gather_kernel(
        const unsigned int* __restrict__ xh, const float* __restrict__ dis,
        const int* __restrict__ offset, const int* __restrict__ deg,
        const unsigned int* __restrict__ payload, unsigned int* __restrict__ agg, int N) {
    int node = blockIdx.x * 4 + (threadIdx.x >> 6);
    int lane = threadIdx.x & 63;
    if (node >= N) return;

    float dn = dis[node];
    float w0 = dn * dn;                       // self-loop norm
    unsigned int sv = xh[(long long)node * C2U + lane];
    float accx = w0 * bflo(sv);
    float accy = w0 * bfhi(sv);

    int beg = offset[node];
    int cnt = deg[node];

    unsigned int e0, e1, e2, e3;
    int i = 0;
    if (cnt >= 4) {
        e0 = payload[beg + 0]; e1 = payload[beg + 1];
        e2 = payload[beg + 2]; e3 = payload[beg + 3];
        while (i + 4 <= cnt) {
            unsigned int c0 = e0, c1 = e1, c2 = e2, c3 = e3;
            int nb = beg + i + 4;
            if (i + 8 <= cnt) {                 // prefetch next payload group
                e0 = payload[nb + 0]; e1 = payload[nb + 1];
                e2 = payload[nb + 2]; e3 = payload[nb + 3];
            }
            unsigned int v0 = xh[(long long)pk_src(c0) * C2U + lane];
            unsigned int v1 = xh[(long long)pk_src(c1) * C2U + lane];
            unsigned int v2 = xh[(long long)pk_src(c2) * C2U + lane];
            unsigned int v3 = xh[(long long)pk_src(c3) * C2U + lane];
            float f0 = pk_w(c0), f1 = pk_w(c1), f2 = pk_w(c2), f3 = pk_w(c3);
            accx += f0 * bflo(v0); accy += f0 * bfhi(v0);
            accx += f1 * bflo(v1); accy += f1 * bfhi(v1);
            accx += f2 * bflo(v2); accy += f2 * bfhi(v2);
            accx += f3 * bflo(v3); accy += f3 * bfhi(v3);
            i += 4;
        }
    }
    for (; i < cnt; ++i) {
        unsigned int curp = payload[beg + i];
        float w = pk_w(curp);
        unsigned int v = xh[(long long)pk_src(curp) * C2U + lane];
        accx += w * bflo(v);
        accy += w * bfhi(v);
    }
    agg[(long long)node * C2U + lane] = f2bf(accx) | (f2bf(accy) << 16);
}

__device__ __forceinline__ float silu1(float v) {
    return v / (1.0f + __expf(-v));
}

// ---------------- MFMA GEMM: out = silu(agg @ W + b) ----------------
__global__ __launch_bounds__(256, 2) void ngl_mfma_gemm_kernel(
        const uint4* __restrict__ agg4, const uint4* __restrict__ wt4,
        const float* __restrict__ bias, float* __restrict__ out,
        int N, int tiles_total) {
    int wid  = threadIdx.x >> 6;
    int lane = threadIdx.x & 63;
    int r  = lane & 15;       // row-in-tile (A) / col-in-tile (B,D)
    int kg = lane >> 4;       // k-group 0..3

    bf16x8 bfr[8][4];
    #pragma unroll
    for (int nt = 0; nt < 8; ++nt) {
        #pragma unroll
        for (int kk = 0; kk < 4; ++kk) {
            UV u; u.u = wt4[(nt * 16 + r) * 16 + kk * 4 + kg];
            bfr[nt][kk] = u.h;
        }
    }
    float bv[8];
    #pragma unroll
    for (int nt = 0; nt < 8; ++nt) bv[nt] = bias[nt * 16 + r];

    for (int tile = blockIdx.x * 4 + wid; tile < tiles_total; tile += gridDim.x * 4) {
        int row0 = tile * 16;
        int arow = row0 + r;

        bf16x8 afr[4];
        #pragma unroll
        for (int kk = 0; kk < 4; ++kk) {
            UV u;
            u.u = (arow < N) ? agg4[(long long)arow * 16 + kk * 4 + kg]
                             : make_uint4(0, 0, 0, 0);
            afr[kk] = u.h;
        }

        f32x4 acc[8];
        #pragma unroll
        for (int nt = 0; nt < 8; ++nt) acc[nt] = (f32x4){0.f, 0.f, 0.f, 0.f};

        #pragma unroll
        for (int kk = 0; kk < 4; ++kk) {
            #pragma unroll
            for (int nt = 0; nt < 8; ++nt) {
                acc[nt] = __builtin_amdgcn_mfma_f32_16x16x32_bf16(
                    afr[kk], bfr[nt][kk], acc[nt], 0, 0, 0);
            }
        }

        #pragma unroll
        for (int nt = 0; nt < 8; ++nt) {
            #pragma unroll
            for (int j = 0; j < 4; ++j) {
                int rr = row0 + kg * 4 + j;
                if (rr < N)
                    __builtin_nontemporal_store(
                        silu1(acc[nt][j] + bv[nt]),
                        &out[(long long)rr * C + nt * 16 + r]);
            }
        }
    }
}

extern "C" void kernel_launch(void* const* d_in, const int* in_sizes, int n_in,
                              void* d_out, int out_size, void* d_ws, size_t ws_size,
                              hipStream_t stream) {
    const float* x = (const float*)d_in[0];
    const int*   ei = (const int*)d_in[1];
    const float* W = (const float*)d_in[2];
    const float* b = (const float*)d_in[3];

    int N = in_sizes[0] / C;
    int E = in_sizes[1] / 2;
    const int* src = ei;
    const int* dst = ei + E;

    int NBUCK = (N + BNODES - 1) / BNODES;        // 782
    int NBLK  = (E + CHUNKE - 1) / CHUNKE;        // 98
    int M     = NBUCK * NBLK;                     // 76,636
    int NB2   = (M + 1023) / 1024;                // 75 (<=256 required)

    char* ws = (char*)d_ws;
    size_t off = 0;
    unsigned int* xh = (unsigned int*)(ws + off);  off += (size_t)N * C * 2;  // 25.6 MB
    unsigned int* agg = (unsigned int*)(ws + off); off += (size_t)N * C * 2;  // 25.6 MB
    unsigned int* pk = (unsigned int*)(ws + off);  off += (size_t)E * 4;      // 6.4 MB
    unsigned int* payload = (unsigned int*)(ws + off); off += (size_t)E * 4;  // 6.4 MB
    int* cnt = (int*)(ws + off);                   off += (size_t)M * 4;      // 0.3 MB
    int* cntoff = (int*)(ws + off);                off += (size_t)M * 4;      // 0.3 MB
    int* s1sum = (int*)(ws + off);                 off += 1024 * 4;
    int* deg = (int*)(ws + off);                   off += (size_t)N * 4;
    int* offset = (int*)(ws + off);                off += (size_t)N * 4;
    float* dis = (float*)(ws + off);               off += (size_t)N * 4;
    unsigned int* Wt = (unsigned int*)(ws + off);  off += (size_t)C * C2U * 4;

    int n8 = N * C / 8;
    int cw = n8 + C * C2U;
    ngl_cvtwt_kernel<<<(cw + 255) / 256, 256, 0, stream>>>(
        (const float4*)x, (uint4*)xh, n8, W, Wt);

    ngl_chist_kernel<<<NBLK, 256, NBUCK * 4, stream>>>(dst, E, NBUCK, NBLK, cnt);
    ngl_s1_kernel<<<NB2, 256, 0, stream>>>(cnt, s1sum, M);
    ngl_s2_kernel<<<NB2, 256, 0, stream>>>(cnt, s1sum, cntoff, M, NB2);
    ngl_cscat_kernel<<<NBLK, 256, NBUCK * 4, stream>>>(src, dst, E, NBUCK, NBLK, cntoff, pk);
    ngl_f1_kernel<<<NBUCK, 256, 0, stream>>>(pk, cntoff, NBLK, E, N, deg, dis);
    ngl_f2_kernel<<<NBUCK, 256, 0, stream>>>(pk, cntoff, NBLK, E, N, dis, offset, payload);

    ngl_gather_kernel<<<(N + 3) / 4, 256, 0, stream>>>(
        xh, dis, offset, deg, payload, agg, N);

    int tiles = (N + 15) / 16;            // 6250
    ngl_mfma_gemm_kernel<<<512, 256, 0, stream>>>(
        (const uint4*)agg, (const uint4*)Wt, b, (float*)d_out, N, tiles);
}

// Round 12
// 181.655 us; speedup vs baseline: 1.3839x; 1.0326x over previous
//
#include <hip/hip_runtime.h>
#include <math.h>

#define C      128
#define C2U    64         // uints (2x bf16) per row
#define BSH    7          // 128 nodes per coarse bucket
#define BNODES 128
#define CHUNKE 16384      // edges per coarse block

typedef __attribute__((ext_vector_type(8))) short bf16x8;   // 8 bf16 = 4 VGPR
typedef __attribute__((ext_vector_type(4))) float f32x4;

union UV { uint4 u; bf16x8 h; };

// ---- bf16 helpers (manual RNE) ----
__device__ __forceinline__ unsigned int f2bf(float f) {
    unsigned int u = __float_as_uint(f);
    return (u + 0x7fffu + ((u >> 16) & 1u)) >> 16;
}
__device__ __forceinline__ float bflo(unsigned int v) { return __uint_as_float(v << 16); }
__device__ __forceinline__ float bfhi(unsigned int v) { return __uint_as_float(v & 0xffff0000u); }

// ---------------- a1: coarse histogram (LDS atomics only) ----------------
__global__ __launch_bounds__(256) void ngl_chist_kernel(
        const int* __restrict__ dst, int E, int NBUCK, int NBLK, int* __restrict__ cnt) {
    extern __shared__ int h[];
    for (int i = threadIdx.x; i < NBUCK; i += 256) h[i] = 0;
    __syncthreads();
    int base = blockIdx.x * CHUNKE;
    int end = base + CHUNKE; if (end > E) end = E;
    for (int i = base + threadIdx.x; i < end; i += 256)
        atomicAdd(&h[dst[i] >> BSH], 1);
    __syncthreads();
    for (int i = threadIdx.x; i < NBUCK; i += 256)
        cnt[i * NBLK + blockIdx.x] = h[i];
}

// ---------------- a2a: partial sums for scan; also hosts W -> W^T bf16 ----------------
__global__ __launch_bounds__(256) void ngl_s1_kernel(const int* __restrict__ in,
                                                     int* __restrict__ bsum, int M,
                                                     const float* __restrict__ W,
                                                     unsigned int* __restrict__ Wt) {
    // piggyback: Wt conversion on the first 32 blocks (8192 elements)
    int g = blockIdx.x * 256 + threadIdx.x;
    if (g < C * C2U) {
        int col = g >> 6, k2 = g & 63;
        float w0 = W[(2 * k2) * C + col];
        float w1 = W[(2 * k2 + 1) * C + col];
        Wt[col * C2U + k2] = f2bf(w0) | (f2bf(w1) << 16);
    }

    __shared__ int red[256];
    int t = threadIdx.x;
    int base = blockIdx.x * 1024 + t * 4;
    int s = 0;
    #pragma unroll
    for (int j = 0; j < 4; ++j) {
        int i = base + j;
        if (i < M) s += in[i];
    }
    red[t] = s;
    __syncthreads();
    for (int o = 128; o > 0; o >>= 1) {
        if (t < o) red[t] += red[t + o];
        __syncthreads();
    }
    if (t == 0) bsum[blockIdx.x] = red[0];
}

// ---------------- a2b: exclusive scan (redundant block-sum scan in LDS) ----------------
__global__ __launch_bounds__(256) void ngl_s2_kernel(
        const int* __restrict__ in, const int* __restrict__ bsum,
        int* __restrict__ out, int M, int NB) {
    __shared__ int pre[256];
    __shared__ int red[256];
    int t = threadIdx.x;
    pre[t] = (t < NB) ? bsum[t] : 0;
    __syncthreads();
    for (int o = 1; o < 256; o <<= 1) {
        int v = 0;
        if (t >= o) v = pre[t - o];
        __syncthreads();
        if (t >= o) pre[t] += v;
        __syncthreads();
    }
    int boff = (blockIdx.x == 0) ? 0 : pre[blockIdx.x - 1];

    int base = blockIdx.x * 1024 + t * 4;
    int v[4];
    int s = 0;
    #pragma unroll
    for (int j = 0; j < 4; ++j) {
        int i = base + j;
        v[j] = (i < M) ? in[i] : 0;
        s += v[j];
    }
    red[t] = s;
    __syncthreads();
    for (int o = 1; o < 256; o <<= 1) {
        int u = 0;
        if (t >= o) u = red[t - o];
        __syncthreads();
        if (t >= o) red[t] += u;
        __syncthreads();
    }
    int run = boff + ((t == 0) ? 0 : red[t - 1]);
    #pragma unroll
    for (int j = 0; j < 4; ++j) {
        int i = base + j;
        if (i < M) {
            out[i] = run;
            run += v[j];
        }
    }
}

// ---------------- a3: coarse scatter; pk = src | dstloc<<17 ----------------
__global__ __launch_bounds__(256) void ngl_cscat_kernel(
        const int* __restrict__ src, const int* __restrict__ dst, int E,
        int NBUCK, int NBLK, const int* __restrict__ cntoff,
        unsigned int* __restrict__ pk) {
    extern __shared__ int cur[];
    int blk = blockIdx.x;
    for (int i = threadIdx.x; i < NBUCK; i += 256) cur[i] = cntoff[i * NBLK + blk];
    __syncthreads();
    int base = blk * CHUNKE;
    int end = base + CHUNKE; if (end > E) end = E;
    for (int i = base + threadIdx.x; i < end; i += 256) {
        int d = dst[i];
        int b = d >> BSH;
        int pos = atomicAdd(&cur[b], 1);
        pk[pos] = (unsigned int)src[i] | ((unsigned int)(d & (BNODES - 1)) << 17);
    }
}

// ---------------- f: per-bucket hist -> deg/dis/offset + fine scatter (src only) ----------------
__global__ __launch_bounds__(256) void ngl_fcomb_kernel(
        const unsigned int* __restrict__ pk, const int* __restrict__ cntoff,
        int NBLK, int E, int N,
        int* __restrict__ deg, float* __restrict__ dis,
        int* __restrict__ offset, int* __restrict__ payload) {
    __shared__ int h[BNODES];
    __shared__ int sc[BNODES];
    __shared__ int cur[BNODES];
    int b = blockIdx.x, nb = gridDim.x;
    int s = cntoff[b * NBLK];
    int e = (b + 1 < nb) ? cntoff[(b + 1) * NBLK] : E;
    int t = threadIdx.x;
    if (t < BNODES) h[t] = 0;
    __syncthreads();
    for (int i = s + t; i < e; i += 256)
        atomicAdd(&h[pk[i] >> 17], 1);
    __syncthreads();
    if (t < BNODES) sc[t] = h[t];
    __syncthreads();
    for (int o = 1; o < BNODES; o <<= 1) {
        int v = 0;
        if (t < BNODES && t >= o) v = sc[t - o];
        __syncthreads();
        if (t < BNODES && t >= o) sc[t] += v;
        __syncthreads();
    }
    if (t < BNODES) {
        int ex = (t == 0) ? 0 : sc[t - 1];
        cur[t] = ex;
        int n = b * BNODES + t;
        if (n < N) {
            int dv = h[t];
            deg[n] = dv;
            dis[n] = rsqrtf((float)(dv + 1));
            offset[n] = s + ex;
        }
    }
    __syncthreads();
    for (int i = s + t; i < e; i += 256) {
        unsigned int p = pk[i];
        int loc = (int)(p >> 17);
        int pos = s + atomicAdd(&cur[loc], 1);
        payload[pos] = (int)(p & 0x1FFFFu);
    }
}

// ---------------- cvtx: xh[i] = bf16(x[i] * dis[node]) ----------------
__global__ __launch_bounds__(256) void ngl_cvtx_kernel(
        const float4* __restrict__ x4, const float* __restrict__ dis,
        uint4* __restrict__ xh4, int nt) {
    int t = blockIdx.x * blockDim.x + threadIdx.x;
    if (t >= nt) return;
    int node = t >> 4;                 // 16 threads per 128-wide row
    int q = t & 15;
    float d = dis[node];
    float4 a = x4[node * 32 + q * 2], b = x4[node * 32 + q * 2 + 1];
    uint4 o;
    o.x = f2bf(a.x * d) | (f2bf(a.y * d) << 16);
    o.y = f2bf(a.z * d) | (f2bf(a.w * d) << 16);
    o.z = f2bf(b.x * d) | (f2bf(b.y * d) << 16);
    o.w = f2bf(b.z * d) | (f2bf(b.w * d) << 16);
    xh4[node * 16 + q] = o;
}

// one wave per node; 4-deep pipeline; NO per-edge weight (pre-scaled x):
// agg[n] = bf16( dis[n] * (xh[n] + sum_edges xh[src]) )
__global__ __launch_bounds__(256) void ngl_gather_kernel(
        const unsigned int* __restrict__ xh, const float* __restrict__ dis,
        const int* __restrict__ offset, const int* __restrict__ deg,
        const int* __restrict__ payload, unsigned int* __restrict__ agg, int N) {
    int node = blockIdx.x * 4 + (threadIdx.x >> 6);
    int lane = threadIdx.x & 63;
    if (node >= N) return;

    unsigned int sv = xh[(long long)node * C2U + lane];
    float accx = bflo(sv);
    float accy = bfhi(sv);

    int beg = offset[node];
    int cnt = deg[node];

    int e0, e1, e2, e3;
    int i = 0;
    if (cnt >= 4) {
        e0 = payload[beg + 0]; e1 = payload[beg + 1];
        e2 = payload[beg + 2]; e3 = payload[beg + 3];
        while (i + 4 <= cnt) {
            int c0 = e0, c1 = e1, c2 = e2, c3 = e3;
            int nb = beg + i + 4;
            if (i + 8 <= cnt) {                 // prefetch next payload group
                e0 = payload[nb + 0]; e1 = payload[nb + 1];
                e2 = payload[nb + 2]; e3 = payload[nb + 3];
            }
            unsigned int v0 = xh[(long long)c0 * C2U + lane];
            unsigned int v1 = xh[(long long)c1 * C2U + lane];
            unsigned int v2 = xh[(long long)c2 * C2U + lane];
            unsigned int v3 = xh[(long long)c3 * C2U + lane];
            accx += bflo(v0); accy += bfhi(v0);
            accx += bflo(v1); accy += bfhi(v1);
            accx += bflo(v2); accy += bfhi(v2);
            accx += bflo(v3); accy += bfhi(v3);
            i += 4;
        }
    }
    for (; i < cnt; ++i) {
        int cs = payload[beg + i];
        unsigned int v = xh[(long long)cs * C2U + lane];
        accx += bflo(v);
        accy += bfhi(v);
    }
    float dn = dis[node];
    agg[(long long)node * C2U + lane] = f2bf(accx * dn) | (f2bf(accy * dn) << 16);
}

__device__ __forceinline__ float silu1(float v) {
    return v / (1.0f + __expf(-v));
}

// ---------------- MFMA GEMM: out = silu(agg @ W + b) ----------------
__global__ __launch_bounds__(256, 2) void ngl_mfma_gemm_kernel(
        const uint4* __restrict__ agg4, const uint4* __restrict__ wt4,
        const float* __restrict__ bias, float* __restrict__ out,
        int N, int tiles_total) {
    int wid  = threadIdx.x >> 6;
    int lane = threadIdx.x & 63;
    int r  = lane & 15;       // row-in-tile (A) / col-in-tile (B,D)
    int kg = lane >> 4;       // k-group 0..3

    bf16x8 bfr[8][4];
    #pragma unroll
    for (int nt = 0; nt < 8; ++nt) {
        #pragma unroll
        for (int kk = 0; kk < 4; ++kk) {
            UV u; u.u = wt4[(nt * 16 + r) * 16 + kk * 4 + kg];
            bfr[nt][kk] = u.h;
        }
    }
    float bv[8];
    #pragma unroll
    for (int nt = 0; nt < 8; ++nt) bv[nt] = bias[nt * 16 + r];

    for (int tile = blockIdx.x * 4 + wid; tile < tiles_total; tile += gridDim.x * 4) {
        int row0 = tile * 16;
        int arow = row0 + r;

        bf16x8 afr[4];
        #pragma unroll
        for (int kk = 0; kk < 4; ++kk) {
            UV u;
            u.u = (arow < N) ? agg4[(long long)arow * 16 + kk * 4 + kg]
                             : make_uint4(0, 0, 0, 0);
            afr[kk] = u.h;
        }

        f32x4 acc[8];
        #pragma unroll
        for (int nt = 0; nt < 8; ++nt) acc[nt] = (f32x4){0.f, 0.f, 0.f, 0.f};

        #pragma unroll
        for (int kk = 0; kk < 4; ++kk) {
            #pragma unroll
            for (int nt = 0; nt < 8; ++nt) {
                acc[nt] = __builtin_amdgcn_mfma_f32_16x16x32_bf16(
                    afr[kk], bfr[nt][kk], acc[nt], 0, 0, 0);
            }
        }

        #pragma unroll
        for (int nt = 0; nt < 8; ++nt) {
            #pragma unroll
            for (int j = 0; j < 4; ++j) {
                int rr = row0 + kg * 4 + j;
                if (rr < N)
                    __builtin_nontemporal_store(
                        silu1(acc[nt][j] + bv[nt]),
                        &out[(long long)rr * C + nt * 16 + r]);
            }
        }
    }
}

extern "C" void kernel_launch(void* const* d_in, const int* in_sizes, int n_in,
                              void* d_out, int out_size, void* d_ws, size_t ws_size,
                              hipStream_t stream) {
    const float* x = (const float*)d_in[0];
    const int*   ei = (const int*)d_in[1];
    const float* W = (const float*)d_in[2];
    const float* b = (const float*)d_in[3];

    int N = in_sizes[0] / C;
    int E = in_sizes[1] / 2;
    const int* src = ei;
    const int* dst = ei + E;

    int NBUCK = (N + BNODES - 1) / BNODES;        // 782
    int NBLK  = (E + CHUNKE - 1) / CHUNKE;        // 98
    int M     = NBUCK * NBLK;                     // 76,636
    int NB2   = (M + 1023) / 1024;                // 75 (<=256 required)

    char* ws = (char*)d_ws;
    size_t off = 0;
    unsigned int* xh = (unsigned int*)(ws + off);  off += (size_t)N * C * 2;  // 25.6 MB
    unsigned int* agg = (unsigned int*)(ws + off); off += (size_t)N * C * 2;  // 25.6 MB
    unsigned int* pk = (unsigned int*)(ws + off);  off += (size_t)E * 4;      // 6.4 MB
    int* payload = (int*)(ws + off);               off += (size_t)E * 4;      // 6.4 MB
    int* cnt = (int*)(ws + off);                   off += (size_t)M * 4;      // 0.3 MB
    int* cntoff = (int*)(ws + off);                off += (size_t)M * 4;      // 0.3 MB
    int* s1sum = (int*)(ws + off);                 off += 1024 * 4;
    int* deg = (int*)(ws + off);                   off += (size_t)N * 4;
    int* offset = (int*)(ws + off);                off += (size_t)N * 4;
    float* dis = (float*)(ws + off);               off += (size_t)N * 4;
    unsigned int* Wt = (unsigned int*)(ws + off);  off += (size_t)C * C2U * 4;

    ngl_chist_kernel<<<NBLK, 256, NBUCK * 4, stream>>>(dst, E, NBUCK, NBLK, cnt);
    ngl_s1_kernel<<<NB2, 256, 0, stream>>>(cnt, s1sum, M, W, Wt);
    ngl_s2_kernel<<<NB2, 256, 0, stream>>>(cnt, s1sum, cntoff, M, NB2);
    ngl_cscat_kernel<<<NBLK, 256, NBUCK * 4, stream>>>(src, dst, E, NBUCK, NBLK, cntoff, pk);
    ngl_fcomb_kernel<<<NBUCK, 256, 0, stream>>>(pk, cntoff, NBLK, E, N, deg, dis, offset, payload);

    int ntx = N * 16;
    ngl_cvtx_kernel<<<(ntx + 255) / 256, 256, 0, stream>>>(
        (const float4*)x, dis, (uint4*)xh, ntx);

    ngl_gather_kernel<<<(N + 3) / 4, 256, 0, stream>>>(
        xh, dis, offset, deg, payload, agg, N);

    int tiles = (N + 15) / 16;            // 6250
    ngl_mfma_gemm_kernel<<<512, 256, 0, stream>>>(
        (const uint4*)agg, (const uint4*)Wt, b, (float*)d_out, N, tiles);
}